// Round 13
// baseline (321.698 us; speedup 1.0000x reference)
//
#include <hip/hip_runtime.h>

#define N_NODES 10000
#define BATCH   8
#define IN_SZ   64
#define UNITS   64
#define ROW_U   256            // uints per bf16 row (512 bf16 = 4 stripes of 64)
#define RCAP    96             // fixed per-row edge capacity (P(deg>96) ~ 1e-18)
#define STR     (N_NODES * 64) // uints per stripe (640,000)

typedef unsigned int uint;
typedef __attribute__((ext_vector_type(8))) short short8;
typedef __attribute__((ext_vector_type(4))) float float4v;
typedef __attribute__((ext_vector_type(2))) float float2v;
typedef __attribute__((ext_vector_type(2))) uint uint2v;

// ---- bf16 helpers (RNE) ----------------------------------------------------
__device__ inline float bf_lo(uint u) { return __uint_as_float(u << 16); }
__device__ inline float bf_hi(uint u) { return __uint_as_float(u & 0xFFFF0000u); }
__device__ inline uint  f2bf_bits(float f) {
    uint u = __float_as_uint(f);
    uint r = ((u >> 16) & 1u) + 0x7FFFu;
    return (u + r) >> 16;
}
__device__ inline uint pack2(float a, float b) {
    return f2bf_bits(a) | (f2bf_bits(b) << 16);
}

// ---------------------------------------------------------------------------
// k_transpose_scatter: transpose in[b,n,i] fp32 -> x0 stripe layout bf16;
// scatter COO edges into fixed 96-slot row buckets. (unchanged from r12)
// ---------------------------------------------------------------------------
__global__ __launch_bounds__(256) void k_transpose_scatter(
    const float2v* __restrict__ in2, uint* __restrict__ x0,
    const int* __restrict__ rows, const int* __restrict__ cols,
    const float* __restrict__ vals, int* __restrict__ cursor,
    uint2v* __restrict__ edges, int nnz) {
    int gid = blockIdx.x * 256 + threadIdx.x;      // 2,560,000 total
    if (gid < nnz) {
        int r   = rows[gid];
        int pos = r * RCAP + atomicAdd(&cursor[r], 1);
        uint2v ev;
        ev.x = (uint)cols[gid];
        ev.y = __float_as_uint(vals[gid]);
        edges[pos] = ev;
    }
    int n  = gid >> 8;          // node
    int b  = (gid >> 5) & 7;    // batch
    int iu = gid & 31;
    float2v v = __builtin_nontemporal_load(&in2[(size_t)b * (N_NODES * 32) +
                                                (size_t)n * 32 + iu]);
    int q = (gid >> 6) & 3;     // stripe
    x0[(size_t)q * STR + (size_t)n * 64 + (gid & 63)] = pack2(v.x, v.y);
}

// ---------------------------------------------------------------------------
// k_spmm_rep: IDENTICAL math to r12's k_spmm but executes the whole SpMM
// `rep` times (same inputs -> same outputs; x1 written rep times).
// DIAGNOSTIC: dur ~= rep*S so it (a) measures S exactly via dur_us delta and
// (b) surfaces real counters in the top-5. NO __restrict__ here: the x1
// stores may alias the loads as far as the compiler knows, so iterations
// cannot be CSE'd away.
// ---------------------------------------------------------------------------
__global__ __launch_bounds__(256) void k_spmm_rep(const int* cursor,
                                                  const uint2v* edges,
                                                  const uint* xin,
                                                  uint* xout,
                                                  const uint* xsub,
                                                  float scale, int rep) {
    int wave = threadIdx.x >> 6;
    int lane = threadIdx.x & 63;
    int row  = blockIdx.x * 4 + wave;
    int q    = blockIdx.y;

    for (int it = 0; it < rep; ++it) {
        const uint* xq = xin + (size_t)q * STR;
        int base = row * RCAP;
        int cnt  = __builtin_amdgcn_readfirstlane(cursor[row]);

        float2v acc = {0.f, 0.f};

        int full_end = base + (cnt & ~7);
        for (int e = base; e < full_end; e += 8) {
            uint2v ev[8];
#pragma unroll
            for (int j = 0; j < 8; ++j) ev[j] = edges[e + j];
            uint x[8];
#pragma unroll
            for (int j = 0; j < 8; ++j)
                x[j] = xq[(size_t)ev[j].x * 64 + lane];
#pragma unroll
            for (int j = 0; j < 8; ++j) {
                float vj = __uint_as_float(ev[j].y);
                float2v vv = {vj, vj};
                float2v pp = {bf_lo(x[j]), bf_hi(x[j])};
                acc += vv * pp;
            }
        }
        int rem = cnt & 7;
        if (rem) {
            int e = full_end;
            uint2v ev[8];
#pragma unroll
            for (int j = 0; j < 8; ++j) ev[j] = edges[e + j];
            uint x[8];
#pragma unroll
            for (int j = 0; j < 8; ++j) {
                uint c = ev[j].x & 16383u;
                if (c >= N_NODES) c = 0;
                x[j] = xq[(size_t)c * 64 + lane];
            }
#pragma unroll
            for (int j = 0; j < 8; ++j) {
                float vj = (j < rem) ? __uint_as_float(ev[j].y) : 0.f;
                float2v vv = {vj, vj};
                float2v pp = {bf_lo(x[j]), bf_hi(x[j])};
                acc += vv * pp;
            }
        }

        float o0 = scale * acc.x, o1 = scale * acc.y;
        if (xsub) {
            uint sx = __builtin_nontemporal_load(
                &xsub[(size_t)q * STR + (size_t)row * 64 + lane]);
            o0 -= bf_lo(sx);
            o1 -= bf_hi(sx);
        }
        __builtin_nontemporal_store(pack2(o0, o1),
            &xout[(size_t)q * STR + (size_t)row * 64 + lane]);
    }
}

// ---------------------------------------------------------------------------
// k_spmm: r12's production SpMM (used for spmm2, unchanged).
// ---------------------------------------------------------------------------
__global__ __launch_bounds__(256) void k_spmm(const int* __restrict__ cursor,
                                              const uint2v* __restrict__ edges,
                                              const uint* __restrict__ xin,
                                              uint* __restrict__ xout,
                                              const uint* __restrict__ xsub,
                                              float scale) {
    int wave = threadIdx.x >> 6;
    int lane = threadIdx.x & 63;
    int row  = blockIdx.x * 4 + wave;
    int q    = blockIdx.y;

    const uint* xq = xin + (size_t)q * STR;
    int base = row * RCAP;
    int cnt  = __builtin_amdgcn_readfirstlane(cursor[row]);

    float2v acc = {0.f, 0.f};

    int full_end = base + (cnt & ~7);
    for (int e = base; e < full_end; e += 8) {
        uint2v ev[8];
#pragma unroll
        for (int j = 0; j < 8; ++j) ev[j] = edges[e + j];   // uniform -> s_load
        uint x[8];
#pragma unroll
        for (int j = 0; j < 8; ++j)
            x[j] = xq[(size_t)ev[j].x * 64 + lane];
#pragma unroll
        for (int j = 0; j < 8; ++j) {
            float vj = __uint_as_float(ev[j].y);
            float2v vv = {vj, vj};
            float2v pp = {bf_lo(x[j]), bf_hi(x[j])};
            acc += vv * pp;
        }
    }
    int rem = cnt & 7;
    if (rem) {
        int e = full_end;
        uint2v ev[8];
#pragma unroll
        for (int j = 0; j < 8; ++j) ev[j] = edges[e + j];
        uint x[8];
#pragma unroll
        for (int j = 0; j < 8; ++j) {
            uint c = ev[j].x & 16383u;
            if (c >= N_NODES) c = 0;
            x[j] = xq[(size_t)c * 64 + lane];
        }
#pragma unroll
        for (int j = 0; j < 8; ++j) {
            float vj = (j < rem) ? __uint_as_float(ev[j].y) : 0.f;
            float2v vv = {vj, vj};
            float2v pp = {bf_lo(x[j]), bf_hi(x[j])};
            acc += vv * pp;
        }
    }

    float o0 = scale * acc.x, o1 = scale * acc.y;
    if (xsub) {
        uint sx = __builtin_nontemporal_load(
            &xsub[(size_t)q * STR + (size_t)row * 64 + lane]);
        o0 -= bf_lo(sx);
        o1 -= bf_hi(sx);
    }
    __builtin_nontemporal_store(pack2(o0, o1),
        &xout[(size_t)q * STR + (size_t)row * 64 + lane]);
}

// ---------------------------------------------------------------------------
// k_combine (MFMA): unchanged from r12.
// ---------------------------------------------------------------------------
__global__ __launch_bounds__(256) void k_combine(const uint* __restrict__ x0,
                                                 const uint* __restrict__ x1,
                                                 const uint* __restrict__ x2,
                                                 const float* __restrict__ W,
                                                 const float* __restrict__ bias,
                                                 float* __restrict__ out) {
    __shared__ unsigned short sWt[64][200];    // [u][k] bf16, pad 192->200 (25.6 KB)
    int t = threadIdx.x;
    for (int e = t; e < 192 * 64; e += 256) {
        int f = e >> 6;                        // fan_in row = i*3 + m
        int u = e & 63;
        int i = f / 3;
        int m = f - 3 * i;
        sWt[u][m * 64 + i] = (unsigned short)f2bf_bits(W[e]);
    }
    __syncthreads();

    int wave = t >> 6, lane = t & 63;
    int mrow = lane & 15, quad = lane >> 4;
    int n0   = blockIdx.x * 64 + wave * 16;
    int b    = blockIdx.y;

    const uint* xs[3] = {x0, x1, x2};
    int an = n0 + mrow;
    if (an > N_NODES - 1) an = N_NODES - 1;    // clamp tail reads

    short8 af[6];
#pragma unroll
    for (int kb = 0; kb < 6; ++kb) {
        int mat = kb >> 1;
        int c_u = b * 32 + (kb & 1) * 16 + quad * 4;      // column uint index
        int q   = c_u >> 6;                               // = b>>1
        af[kb] = __builtin_nontemporal_load(
            (const short8*)(xs[mat] + (size_t)q * STR + (size_t)an * 64 +
                            (c_u & 63)));
    }

    float4v acc[4];
#pragma unroll
    for (int ut = 0; ut < 4; ++ut) acc[ut] = (float4v){0.f, 0.f, 0.f, 0.f};

#pragma unroll
    for (int kb = 0; kb < 6; ++kb)
#pragma unroll
        for (int ut = 0; ut < 4; ++ut)
            acc[ut] = __builtin_amdgcn_mfma_f32_16x16x32_bf16(
                af[kb],
                *(const short8*)&sWt[ut * 16 + mrow][kb * 32 + quad * 8],
                acc[ut], 0, 0, 0);

#pragma unroll
    for (int ut = 0; ut < 4; ++ut) {
        float bv = bias[ut * 16 + mrow];
        int u = ut * 16 + mrow;
#pragma unroll
        for (int r = 0; r < 4; ++r) {
            int n = n0 + quad * 4 + r;
            if (n < N_NODES)
                __builtin_nontemporal_store(acc[ut][r] + bv,
                    &out[((size_t)b * N_NODES + n) * UNITS + u]);
        }
    }
}

// ---------------------------------------------------------------------------
extern "C" void kernel_launch(void* const* d_in, const int* in_sizes, int n_in,
                              void* d_out, int out_size, void* d_ws, size_t ws_size,
                              hipStream_t stream) {
    const float* inputs = (const float*)d_in[0];
    const int*   rows   = (const int*)d_in[1];
    const int*   cols   = (const int*)d_in[2];
    const float* vals   = (const float*)d_in[3];
    const float* W      = (const float*)d_in[4];
    const float* bias   = (const float*)d_in[5];
    float*       out    = (float*)d_out;
    int nnz = in_sizes[1];

    char* p = (char*)d_ws;
    auto alloc = [&](size_t bytes) {
        char* r = p;
        p += (bytes + 255) & ~(size_t)255;
        return r;
    };
    uint*   x0     = (uint*)alloc(sizeof(uint) * (size_t)N_NODES * ROW_U);
    uint*   x1     = (uint*)alloc(sizeof(uint) * (size_t)N_NODES * ROW_U);
    uint*   x2     = (uint*)alloc(sizeof(uint) * (size_t)N_NODES * ROW_U);
    int*    cursor = (int*)alloc(sizeof(int) * N_NODES);
    uint2v* edges  = (uint2v*)alloc(sizeof(uint2v) * (size_t)N_NODES * RCAP);

    (void)hipMemsetAsync(cursor, 0, sizeof(int) * N_NODES, stream);
    k_transpose_scatter<<<N_NODES, 256, 0, stream>>>((const float2v*)inputs, x0,
                                                     rows, cols, vals, cursor,
                                                     edges, nnz);
    dim3 sgrid(N_NODES / 4, 4);
    // DIAGNOSTIC: spmm1 executed 5x inside one dispatch (same output).
    k_spmm_rep<<<sgrid, 256, 0, stream>>>(cursor, edges, x0, x1, nullptr,
                                          1.0f, 5);
    k_spmm<<<sgrid, 256, 0, stream>>>(cursor, edges, x1, x2, x0, 2.0f);
    dim3 cgrid((N_NODES + 63) / 64, BATCH);
    k_combine<<<cgrid, 256, 0, stream>>>(x0, x1, x2, W, bias, out);
}

// Round 14
// 184.250 us; speedup vs baseline: 1.7460x; 1.7460x over previous
//
#include <hip/hip_runtime.h>

#define N_NODES 10000
#define BATCH   8
#define IN_SZ   64
#define UNITS   64
#define ROW_U   256            // uints per bf16 row (512 bf16 = 4 stripes of 64)
#define RCAP    96             // fixed per-row edge capacity (P(deg>96) ~ 1e-18)
#define STR     (N_NODES * 64) // uints per stripe (640,000)

typedef unsigned int uint;
typedef __attribute__((ext_vector_type(8))) short short8;
typedef __attribute__((ext_vector_type(4))) float float4v;
typedef __attribute__((ext_vector_type(2))) float float2v;

// ---- bf16 helpers (RNE) ----------------------------------------------------
__device__ inline float bf_lo(uint u) { return __uint_as_float(u << 16); }
__device__ inline float bf_hi(uint u) { return __uint_as_float(u & 0xFFFF0000u); }
__device__ inline uint  f2bf_bits(float f) {
    uint u = __float_as_uint(f);
    uint r = ((u >> 16) & 1u) + 0x7FFFu;
    return (u + r) >> 16;
}
__device__ inline uint pack2(float a, float b) {
    return f2bf_bits(a) | (f2bf_bits(b) << 16);
}

// ---------------------------------------------------------------------------
// k_transpose_scatter: transpose in[b,n,i] fp32 -> x0 stripe layout bf16;
// scatter COO edges into fixed 96-slot row buckets as PACKED 4-byte records:
// low 14 bits = col, high 16 bits = val as bf16 (bit pattern of fp32>>16).
// ---------------------------------------------------------------------------
__global__ __launch_bounds__(256) void k_transpose_scatter(
    const float2v* __restrict__ in2, uint* __restrict__ x0,
    const int* __restrict__ rows, const int* __restrict__ cols,
    const float* __restrict__ vals, int* __restrict__ cursor,
    uint* __restrict__ edges, int nnz) {
    int gid = blockIdx.x * 256 + threadIdx.x;      // 2,560,000 total
    if (gid < nnz) {
        int r   = rows[gid];
        int pos = r * RCAP + atomicAdd(&cursor[r], 1);
        edges[pos] = (uint)cols[gid] | (f2bf_bits(vals[gid]) << 16);
    }
    int n  = gid >> 8;          // node
    int b  = (gid >> 5) & 7;    // batch
    int iu = gid & 31;
    float2v v = __builtin_nontemporal_load(&in2[(size_t)b * (N_NODES * 32) +
                                                (size_t)n * 32 + iu]);
    int q = (gid >> 6) & 3;     // stripe
    x0[(size_t)q * STR + (size_t)n * 64 + (gid & 63)] = pack2(v.x, v.y);
}

// ---------------------------------------------------------------------------
// k_spmm: one WAVE per (row, stripe); lane owns one uint (2 bf16 cols).
// r13 PMC: VALUBusy 56%, FETCH near-ideal, HBM 5% -> VALU-issue-bound; the
// surplus was 64-bit VALU address math per gather. Fixes here:
//  - 32-bit uint index (scalar col*64 in SALU + one v_add) -> saddr gathers
//  - packed 4B edges: col decode s_and+s_lshl, val = s_and (high half IS the
//    fp32 bits) -- all edge metadata on the scalar pipe, s_load_dwordx8
//  - math: 2 unpack + 2 fmac per uint per edge (vj is SGPR src0)
// ---------------------------------------------------------------------------
__global__ __launch_bounds__(256) void k_spmm(const int* __restrict__ cursor,
                                              const uint* __restrict__ edges,
                                              const uint* __restrict__ xin,
                                              uint* __restrict__ xout,
                                              const uint* __restrict__ xsub,
                                              float scale) {
    int wave = threadIdx.x >> 6;
    uint lane = threadIdx.x & 63;
    int row  = blockIdx.x * 4 + wave;
    int q    = blockIdx.y;

    const uint* xq = xin + (size_t)q * STR;
    int base = row * RCAP;
    int cnt  = __builtin_amdgcn_readfirstlane(cursor[row]);

    float a0 = 0.f, a1 = 0.f;

    int full_end = base + (cnt & ~7);
    int e = base;
    for (; e < full_end; e += 8) {
        uint ep[8];
#pragma unroll
        for (int j = 0; j < 8; ++j) ep[j] = edges[e + j];   // uniform -> s_load
        uint x[8];
#pragma unroll
        for (int j = 0; j < 8; ++j)
            x[j] = xq[(ep[j] & 0x3FFFu) * 64u + lane];      // SALU idx + v_add
#pragma unroll
        for (int j = 0; j < 8; ++j) {
            float vj = __uint_as_float(ep[j] & 0xFFFF0000u); // SALU: bf16->f32
            a0 += vj * bf_lo(x[j]);
            a1 += vj * bf_hi(x[j]);
        }
    }
    int rem = cnt & 7;
    if (rem) {
        uint ep[8];
#pragma unroll
        for (int j = 0; j < 8; ++j) ep[j] = edges[e + j];
        uint x[8];
#pragma unroll
        for (int j = 0; j < 8; ++j) {
            uint c = ep[j] & 0x3FFFu;
            if (c > N_NODES - 1) c = N_NODES - 1;            // s_min (poison)
            x[j] = xq[c * 64u + lane];
        }
#pragma unroll
        for (int j = 0; j < 8; ++j) {
            float vj = (j < rem) ? __uint_as_float(ep[j] & 0xFFFF0000u) : 0.f;
            a0 += vj * bf_lo(x[j]);
            a1 += vj * bf_hi(x[j]);
        }
    }

    float o0 = scale * a0, o1 = scale * a1;
    if (xsub) {
        uint sx = __builtin_nontemporal_load(
            &xsub[(size_t)q * STR + (size_t)row * 64 + lane]);
        o0 -= bf_lo(sx);
        o1 -= bf_hi(sx);
    }
    __builtin_nontemporal_store(pack2(o0, o1),
        &xout[(size_t)q * STR + (size_t)row * 64 + lane]);
}

// ---------------------------------------------------------------------------
// k_combine (MFMA): out[b,n,u] = bias[u] + sum_k A[(b,n), k] * Wp[k, u].
// Grid = (157, 8); stripe layout -> each block reads stripe q = b>>1 only.
// ---------------------------------------------------------------------------
__global__ __launch_bounds__(256) void k_combine(const uint* __restrict__ x0,
                                                 const uint* __restrict__ x1,
                                                 const uint* __restrict__ x2,
                                                 const float* __restrict__ W,
                                                 const float* __restrict__ bias,
                                                 float* __restrict__ out) {
    __shared__ unsigned short sWt[64][200];    // [u][k] bf16, pad 192->200 (25.6 KB)
    int t = threadIdx.x;
    for (int e = t; e < 192 * 64; e += 256) {
        int f = e >> 6;                        // fan_in row = i*3 + m
        int u = e & 63;
        int i = f / 3;
        int m = f - 3 * i;
        sWt[u][m * 64 + i] = (unsigned short)f2bf_bits(W[e]);
    }
    __syncthreads();

    int wave = t >> 6, lane = t & 63;
    int mrow = lane & 15, quad = lane >> 4;
    int n0   = blockIdx.x * 64 + wave * 16;
    int b    = blockIdx.y;

    const uint* xs[3] = {x0, x1, x2};
    int an = n0 + mrow;
    if (an > N_NODES - 1) an = N_NODES - 1;    // clamp tail reads

    short8 af[6];
#pragma unroll
    for (int kb = 0; kb < 6; ++kb) {
        int mat = kb >> 1;
        int c_u = b * 32 + (kb & 1) * 16 + quad * 4;      // column uint index
        int q   = c_u >> 6;                               // = b>>1
        af[kb] = __builtin_nontemporal_load(
            (const short8*)(xs[mat] + (size_t)q * STR + (size_t)an * 64 +
                            (c_u & 63)));
    }

    float4v acc[4];
#pragma unroll
    for (int ut = 0; ut < 4; ++ut) acc[ut] = (float4v){0.f, 0.f, 0.f, 0.f};

#pragma unroll
    for (int kb = 0; kb < 6; ++kb)
#pragma unroll
        for (int ut = 0; ut < 4; ++ut)
            acc[ut] = __builtin_amdgcn_mfma_f32_16x16x32_bf16(
                af[kb],
                *(const short8*)&sWt[ut * 16 + mrow][kb * 32 + quad * 8],
                acc[ut], 0, 0, 0);

#pragma unroll
    for (int ut = 0; ut < 4; ++ut) {
        float bv = bias[ut * 16 + mrow];
        int u = ut * 16 + mrow;
#pragma unroll
        for (int r = 0; r < 4; ++r) {
            int n = n0 + quad * 4 + r;
            if (n < N_NODES)
                __builtin_nontemporal_store(acc[ut][r] + bv,
                    &out[((size_t)b * N_NODES + n) * UNITS + u]);
        }
    }
}

// ---------------------------------------------------------------------------
extern "C" void kernel_launch(void* const* d_in, const int* in_sizes, int n_in,
                              void* d_out, int out_size, void* d_ws, size_t ws_size,
                              hipStream_t stream) {
    const float* inputs = (const float*)d_in[0];
    const int*   rows   = (const int*)d_in[1];
    const int*   cols   = (const int*)d_in[2];
    const float* vals   = (const float*)d_in[3];
    const float* W      = (const float*)d_in[4];
    const float* bias   = (const float*)d_in[5];
    float*       out    = (float*)d_out;
    int nnz = in_sizes[1];

    char* p = (char*)d_ws;
    auto alloc = [&](size_t bytes) {
        char* r = p;
        p += (bytes + 255) & ~(size_t)255;
        return r;
    };
    uint* x0     = (uint*)alloc(sizeof(uint) * (size_t)N_NODES * ROW_U);
    uint* x1     = (uint*)alloc(sizeof(uint) * (size_t)N_NODES * ROW_U);
    uint* x2     = (uint*)alloc(sizeof(uint) * (size_t)N_NODES * ROW_U);
    int*  cursor = (int*)alloc(sizeof(int) * N_NODES);
    uint* edges  = (uint*)alloc(sizeof(uint) * (size_t)N_NODES * RCAP);

    (void)hipMemsetAsync(cursor, 0, sizeof(int) * N_NODES, stream);
    k_transpose_scatter<<<N_NODES, 256, 0, stream>>>((const float2v*)inputs, x0,
                                                     rows, cols, vals, cursor,
                                                     edges, nnz);
    dim3 sgrid(N_NODES / 4, 4);
    k_spmm<<<sgrid, 256, 0, stream>>>(cursor, edges, x0, x1, nullptr, 1.0f);
    k_spmm<<<sgrid, 256, 0, stream>>>(cursor, edges, x1, x2, x0, 2.0f);
    dim3 cgrid((N_NODES + 63) / 64, BATCH);
    k_combine<<<cgrid, 256, 0, stream>>>(x0, x1, x2, W, bias, out);
}